// Round 4
// baseline (40.932 us; speedup 1.0000x reference)
//
#include <hip/hip_runtime.h>
#include <stdint.h>

typedef float float4v __attribute__((ext_vector_type(4)));

// robust criterion parse: int32, else f32, else default -1
__device__ __forceinline__ int read_crit(const void* p) {
    const int ci = *(const int*)p;
    if (ci >= -2 && ci <= 3) return ci;
    const float cf = *(const float*)p;
    if (cf == cf && fabsf(cf) <= 4.0f && cf == truncf(cf)) return (int)cf;
    return -1;
}

// Output layout (all float32):
//   [0, 4KN)     overlaps (K*N, 4)
//   [4KN, 6KN)   tensor_index (K*N, 2)  values k, n as float
//   [6KN, 7KN)   valid (K*N)            1.0 / 0.0
__global__ __launch_bounds__(256) void clocs_kernel(
    const float4v* __restrict__ boxes,   // N x 4 f32
    const float4v* __restrict__ qboxes,  // K x 4 f32
    const float*   __restrict__ s3d,     // N f32
    const float*   __restrict__ s2d,     // K f32
    const float*   __restrict__ dis,     // N f32
    const void*    __restrict__ crit_p,
    float*         __restrict__ out,
    int N, int K)
{
    const int idx = blockIdx.x * blockDim.x + threadIdx.x;
    const int total = (K * N) >> 2;     // 4 pairs per thread; N % 4 == 0
    if (idx >= total) return;

    const int p  = idx << 2;            // flat pair index k*N + n0, n0 % 4 == 0
    const int k  = p / N;
    const int n0 = p - k * N;

    const float4v qb = qboxes[k];
    const float qx1 = qb.x, qy1 = qb.y, qx2 = qb.z, qy2 = qb.w;
    const float qarea = (qx2 - qx1) * (qy2 - qy1);
    const float sc2   = s2d[k];
    const int   crit  = read_crit(crit_p);

    const float4v b0 = boxes[n0 + 0];
    const float4v b1 = boxes[n0 + 1];
    const float4v b2 = boxes[n0 + 2];
    const float4v b3 = boxes[n0 + 3];
    const float4v s3v = *(const float4v*)(s3d + n0);   // n0 % 4 == 0 -> aligned
    const float4v dlv = *(const float4v*)(dis + n0);

    float bx1[4], by1[4], bx2[4], by2[4];
    bx1[0]=b0.x; by1[0]=b0.y; bx2[0]=b0.z; by2[0]=b0.w;
    bx1[1]=b1.x; by1[1]=b1.y; bx2[1]=b1.z; by2[1]=b1.w;
    bx1[2]=b2.x; by1[2]=b2.y; bx2[2]=b2.z; by2[2]=b2.w;
    bx1[3]=b3.x; by1[3]=b3.y; bx2[3]=b3.z; by2[3]=b3.w;

    float4v ov[4];     // one float4 per pair: [c0, c1, c2, c3]
    float4v ix01, ix23;
    float4v vlv;

    #pragma unroll
    for (int j = 0; j < 4; ++j) {
        const float iw = fminf(bx2[j], qx2) - fmaxf(bx1[j], qx1);
        const float ih = fminf(by2[j], qy2) - fmaxf(by1[j], qy1);
        const bool  valid = (iw > 0.0f) && (ih > 0.0f);
        const float inter = iw * ih;
        const float barea = (bx2[j] - bx1[j]) * (by2[j] - by1[j]);
        float ua;
        if (crit == -1)      ua = barea + qarea - inter;
        else if (crit == 0)  ua = barea;
        else if (crit == 1)  ua = qarea;
        else                 ua = 1.0f;
        const float iou = (ua != 0.0f) ? (inter / ua) : 0.0f;

        ov[j].x = valid ? iou : -10.0f;
        ov[j].y = s3v[j];
        ov[j].z = valid ? sc2 : -10.0f;
        ov[j].w = dlv[j];
        vlv[j]  = valid ? 1.0f : 0.0f;
    }

    const float kf = (float)k;
    ix01.x = kf; ix01.y = (float)(n0 + 0); ix01.z = kf; ix01.w = (float)(n0 + 1);
    ix23.x = kf; ix23.y = (float)(n0 + 2); ix23.z = kf; ix23.w = (float)(n0 + 3);

    const size_t KN = (size_t)K * (size_t)N;
    float* ovp = out + (size_t)p * 4;            // 64B-aligned (p % 4 == 0)
    float* ixp = out + KN * 4 + (size_t)p * 2;   // 32B-aligned
    float* vlp = out + KN * 6 + (size_t)p;       // 16B-aligned

    *(float4v*)(ovp +  0) = ov[0];
    *(float4v*)(ovp +  4) = ov[1];
    *(float4v*)(ovp +  8) = ov[2];
    *(float4v*)(ovp + 12) = ov[3];
    *(float4v*)(ixp + 0)  = ix01;
    *(float4v*)(ixp + 4)  = ix23;
    *(float4v*)(vlp)      = vlv;
}

extern "C" void kernel_launch(void* const* d_in, const int* in_sizes, int n_in,
                              void* d_out, int out_size, void* d_ws, size_t ws_size,
                              hipStream_t stream) {
    const float4v* boxes  = (const float4v*)d_in[0];
    const float4v* qboxes = (const float4v*)d_in[1];
    const float*   s3d    = (const float*)d_in[2];
    const float*   s2d    = (const float*)d_in[3];
    const float*   dis    = (const float*)d_in[4];

    const int N = in_sizes[0] / 4;
    const int K = in_sizes[1] / 4;
    const int total = (K * N) / 4;      // threads (4 pairs each)
    const int block = 256;
    const int grid  = (total + block - 1) / block;

    clocs_kernel<<<grid, block, 0, stream>>>(
        boxes, qboxes, s3d, s2d, dis, d_in[5],
        (float*)d_out, N, K);
}

// Round 5
// 27.023 us; speedup vs baseline: 1.5147x; 1.5147x over previous
//
#include <hip/hip_runtime.h>
#include <stdint.h>

typedef float float4v __attribute__((ext_vector_type(4)));
typedef float float2v __attribute__((ext_vector_type(2)));

// robust criterion parse: int32, else f32, else default -1
__device__ __forceinline__ int read_crit(const void* p) {
    const int ci = *(const int*)p;
    if (ci >= -2 && ci <= 3) return ci;
    const float cf = *(const float*)p;
    if (cf == cf && fabsf(cf) <= 4.0f && cf == truncf(cf)) return (int)cf;
    return -1;
}

// Output layout (all float32):
//   [0, 4KN)     overlaps (K*N, 4)
//   [4KN, 6KN)   tensor_index (K*N, 2)  values k, n as float
//   [6KN, 7KN)   valid (K*N)            1.0 / 0.0
//
// Grid: x covers N (one thread per box n), y covers K (one block-row per
// query box k). All global stores are lane-contiguous (float4/float2/float
// per lane), so each wave-store is a minimal set of full segments.
__global__ __launch_bounds__(256) void clocs_kernel(
    const float4v* __restrict__ boxes,   // N x 4 f32
    const float4v* __restrict__ qboxes,  // K x 4 f32
    const float*   __restrict__ s3d,     // N f32
    const float*   __restrict__ s2d,     // K f32
    const float*   __restrict__ dis,     // N f32
    const void*    __restrict__ crit_p,
    float*         __restrict__ out,
    int N, int K)
{
    const int n = blockIdx.x * blockDim.x + threadIdx.x;
    if (n >= N) return;
    const int k = blockIdx.y;

    // wave-uniform query data (broadcast loads)
    const float4v qb = qboxes[k];
    const float qx1 = qb.x, qy1 = qb.y, qx2 = qb.z, qy2 = qb.w;
    const float qarea = (qx2 - qx1) * (qy2 - qy1);
    const float sc2   = s2d[k];
    const int   crit  = read_crit(crit_p);

    // lane-contiguous loads
    const float4v b  = boxes[n];
    const float   s3 = s3d[n];
    const float   dl = dis[n];

    const float iw = fminf(b.z, qx2) - fmaxf(b.x, qx1);
    const float ih = fminf(b.w, qy2) - fmaxf(b.y, qy1);
    const bool  valid = (iw > 0.0f) && (ih > 0.0f);
    const float inter = iw * ih;
    const float barea = (b.z - b.x) * (b.w - b.y);
    float ua;
    if (crit == -1)      ua = barea + qarea - inter;
    else if (crit == 0)  ua = barea;
    else if (crit == 1)  ua = qarea;
    else                 ua = 1.0f;
    const float iou = (ua != 0.0f) ? (inter / ua) : 0.0f;

    float4v ov;
    ov.x = valid ? iou : -10.0f;
    ov.y = s3;
    ov.z = valid ? sc2 : -10.0f;
    ov.w = dl;

    float2v ix;
    ix.x = (float)k;
    ix.y = (float)n;

    const size_t p  = (size_t)k * (size_t)N + (size_t)n;
    const size_t KN = (size_t)K * (size_t)N;

    *(float4v*)(out + p * 4)            = ov;   // overlaps row
    *(float2v*)(out + KN * 4 + p * 2)   = ix;   // tensor_index row
    *(out + KN * 6 + p)                 = valid ? 1.0f : 0.0f;
}

extern "C" void kernel_launch(void* const* d_in, const int* in_sizes, int n_in,
                              void* d_out, int out_size, void* d_ws, size_t ws_size,
                              hipStream_t stream) {
    const float4v* boxes  = (const float4v*)d_in[0];
    const float4v* qboxes = (const float4v*)d_in[1];
    const float*   s3d    = (const float*)d_in[2];
    const float*   s2d    = (const float*)d_in[3];
    const float*   dis    = (const float*)d_in[4];

    const int N = in_sizes[0] / 4;   // 10000
    const int K = in_sizes[1] / 4;   // 500
    const int block = 256;
    dim3 grid((N + block - 1) / block, K, 1);

    clocs_kernel<<<grid, dim3(block, 1, 1), 0, stream>>>(
        boxes, qboxes, s3d, s2d, dis, d_in[5],
        (float*)d_out, N, K);
}